// Round 9
// baseline (366.961 us; speedup 1.0000x reference)
//
#include <hip/hip_runtime.h>
#include <hip/hip_fp16.h>

namespace {
constexpr int NN = 100000;   // nodes
constexpr int NE = 1600000;  // edges
constexpr int NF = 128;      // input feats
constexpr int NC = 40;       // classes (propagated dim after algebraic reorder)
constexpr int HP = 64;       // padded h row: 64 halfs = 128 B = exactly 1 L2 line
constexpr int NB = (NN + 255) / 256;  // node blocks = 391
constexpr int EB = (NE + 255) / 256;  // edge blocks = 6250
constexpr int EPT = 8;                // degcnt edges/thread (8 atomics in flight)
constexpr int DB = 782;               // degcnt blocks: 782*256*8 = 1601536 >= NE
constexpr int DS = DB * 256;          // degcnt grid-stride
constexpr float FIX = 1048576.0f;     // 2^20 fixed-point scale for deg
constexpr int NPB = 51;               // nodes per hop block (51*5 = 255 threads)
constexpr int HB  = (NN + NPB - 1) / NPB;  // hop blocks = 1961
constexpr int TS  = 2048;             // staged pairs per tile (16 KB LDS)
}

struct alignas(16) H8 { __half2 a, b, c, d; };   // 8 halfs = one b128

__device__ inline __half2 f2h2(float x, float y) {
    return __halves2half2(__float2half_rn(x), __float2half_rn(y));
}

// Fused: blocks [0,DB) histogram 8 edges/thread (8 independent value-returning
// u64 atomics in flight per thread — degcnt was atomic-RETURN-latency bound at
// 1 atomic/thread: 21 G/s vs 64 G/s for fire-and-forget); blocks [DB,DB+NB)
// compute H0 = x@W -> fp16 padded rows.
__global__ __launch_bounds__(256, 2) void k_build(const int* __restrict__ col,
                                                  const float* __restrict__ w,
                                                  const float* __restrict__ x,
                                                  const float* __restrict__ W,
                                                  unsigned long long* __restrict__ dc,
                                                  unsigned char* __restrict__ rank,
                                                  __half* __restrict__ h0) {
    if (blockIdx.x < (unsigned)DB) {
        int base = blockIdx.x * 256 + threadIdx.x;
        int cs[EPT];
        float wv[EPT];
        unsigned long long old[EPT];
#pragma unroll
        for (int k = 0; k < EPT; ++k) {        // phase 1: gather (col,w), coalesced
            int e = base + k * DS;
            if (e < NE) { cs[k] = col[e]; wv[k] = w[e]; }
        }
#pragma unroll
        for (int k = 0; k < EPT; ++k) {        // phase 2: 8 atomics back-to-back
            int e = base + k * DS;
            if (e < NE) {
                unsigned long long q = (unsigned long long)(unsigned)(wv[k] * FIX + 0.5f);
                old[k] = atomicAdd(&dc[cs[k]], (1ull << 40) | q);
            }
        }
#pragma unroll
        for (int k = 0; k < EPT; ++k) {        // phase 3: rank stores as returns land
            int e = base + k * DS;
            if (e < NE) rank[e] = (unsigned char)(old[k] >> 40);
        }
    } else {
        int n = (blockIdx.x - DB) * 256 + threadIdx.x;
        if (n >= NN) return;
        const float4* xr = (const float4*)(x + (size_t)n * NF);  // 32 float4
        const float4* W4 = (const float4*)W;                     // row k = 10 float4
        float acc[NC];
#pragma unroll
        for (int j = 0; j < NC; ++j) acc[j] = 0.f;
        for (int k4 = 0; k4 < NF / 4; ++k4) {
            float4 xv = xr[k4];
#pragma unroll
            for (int kk = 0; kk < 4; ++kk) {
                float xk = (kk == 0) ? xv.x : (kk == 1) ? xv.y : (kk == 2) ? xv.z : xv.w;
                int k = k4 * 4 + kk;
#pragma unroll
                for (int j4 = 0; j4 < 10; ++j4) {
                    float4 wq = W4[k * 10 + j4];   // wave-uniform address
                    acc[j4 * 4 + 0] += xk * wq.x;
                    acc[j4 * 4 + 1] += xk * wq.y;
                    acc[j4 * 4 + 2] += xk * wq.z;
                    acc[j4 * 4 + 3] += xk * wq.w;
                }
            }
        }
        H8* o = (H8*)(h0 + (size_t)n * HP);
#pragma unroll
        for (int g = 0; g < 5; ++g) {   // 5 x 8 halfs = 40
            H8 v;
            v.a = f2h2(acc[g * 8 + 0], acc[g * 8 + 1]);
            v.b = f2h2(acc[g * 8 + 2], acc[g * 8 + 3]);
            v.c = f2h2(acc[g * 8 + 4], acc[g * 8 + 5]);
            v.d = f2h2(acc[g * 8 + 6], acc[g * 8 + 7]);
            o[g] = v;
        }
    }
}

// Block-local exclusive scan of counts -> offs + bsum; deg -> dis; the LAST
// block to finish (device atomic on `done`) scans bsum[NB] in LDS — replaces
// the separate scan2 dispatch. Consumers add bsum[i>>8] inline.
__global__ __launch_bounds__(256) void k_scan(const unsigned long long* __restrict__ dc,
                                              int* __restrict__ offs,
                                              int* __restrict__ bsum,
                                              float* __restrict__ dis,
                                              int* __restrict__ done) {
    __shared__ int s[256];
    __shared__ int amLast;
    int t = threadIdx.x, i = blockIdx.x * 256 + t;
    unsigned long long p = (i < NN) ? dc[i] : 0ull;
    int v = (int)(p >> 40);
    if (i < NN) {
        float d = (float)(p & ((1ull << 40) - 1)) * (1.0f / FIX);
        dis[i] = (d > 0.f) ? rsqrtf(d) : 0.f;
    }
    s[t] = v;
    __syncthreads();
    for (int off = 1; off < 256; off <<= 1) {
        int add = (t >= off) ? s[t - off] : 0;
        __syncthreads();
        s[t] += add;
        __syncthreads();
    }
    if (i < NN) offs[i] = s[t] - v;
    if (t == 255) bsum[blockIdx.x] = s[255];
    // ---- last-block-done: scan bsum in place ----
    __threadfence();
    if (t == 0) amLast = (atomicAdd(done, 1) == NB - 1) ? 1 : 0;
    __syncthreads();
    if (!amLast) return;
    __threadfence();
    __shared__ int a[512], b[512];
    int i0 = t, i1 = t + 256;
    int v0 = (i0 < NB) ? bsum[i0] : 0;
    int v1 = (i1 < NB) ? bsum[i1] : 0;
    a[i0] = v0; a[i1] = v1;
    __syncthreads();
    int* cur = a; int* nxt = b;
    for (int off = 1; off < 512; off <<= 1) {
        nxt[i0] = cur[i0] + ((i0 >= off) ? cur[i0 - off] : 0);
        nxt[i1] = cur[i1] + ((i1 >= off) ? cur[i1 - off] : 0);
        __syncthreads();
        int* tmp = cur; cur = nxt; nxt = tmp;
    }
    if (i0 < NB) bsum[i0] = cur[i0] - v0;   // exclusive
    if (i1 < NB) bsum[i1] = cur[i1] - v1;
}

// CSR scatter, atomic-free: slot = offs[c] + bsum[c>>8] + rank[e].
// Fused {row, norm} as one 8 B NONTEMPORAL store.
__global__ __launch_bounds__(256) void k_scatter(const int* __restrict__ row,
                                                 const int* __restrict__ col,
                                                 const float* __restrict__ w,
                                                 const float* __restrict__ dis,
                                                 const int* __restrict__ offs,
                                                 const int* __restrict__ bsum,
                                                 const unsigned char* __restrict__ rank,
                                                 int2* __restrict__ pair) {
    int e = blockIdx.x * 256 + threadIdx.x;
    if (e >= NE) return;
    int r = row[e], c = col[e];
    int p = offs[c] + bsum[c >> 8] + rank[e];
    unsigned long long v = (unsigned long long)(unsigned)r |
        ((unsigned long long)(unsigned)__float_as_int(dis[r] * w[e] * dis[c]) << 32);
    __builtin_nontemporal_store(v, (unsigned long long*)(pair + p));
}

// LDS-staged pull hop. Block = 51 nodes x 5 threads; block's CSR segment is
// contiguous -> stage pairs into LDS (1 coalesced VMEM/edge), gather h rows
// with one b128/lane. VMEM/edge = 6.
template <bool FINAL>
__global__ __launch_bounds__(256) void k_hop(const int* __restrict__ offs,
                                             const int* __restrict__ bsum,
                                             const int2* __restrict__ pair,
                                             const __half* __restrict__ hin,
                                             __half* __restrict__ houth,
                                             float* __restrict__ houtf) {
    __shared__ int2 tile[TS];
    __shared__ int erange[2];
    int t = threadIdx.x;
    int g = t / 5;                      // local node 0..50
    int n = blockIdx.x * NPB + g;
    bool active = (t < NPB * 5) && (n < NN);
    int vo = (t - g * 5) * 8;           // half offset 0,8,16,24,32
    int s0 = 0, s1 = 0;
    if (active) {
        s0 = offs[n] + bsum[n >> 8];
        int np = n + 1;
        s1 = (np == NN) ? NE : (offs[np] + bsum[np >> 8]);
    }
    if (t == 0) {
        int n0 = blockIdx.x * NPB;
        erange[0] = offs[n0] + bsum[n0 >> 8];
        int nl = n0 + NPB;
        erange[1] = (nl >= NN) ? NE : (offs[nl] + bsum[nl >> 8]);
    }
    __syncthreads();
    int E0 = erange[0], E1 = erange[1];
    float acc[8];
#pragma unroll
    for (int j = 0; j < 8; ++j) acc[j] = 0.f;
    int i = s0;
    for (int t0 = E0; t0 < E1; t0 += TS) {
        int lim = min(t0 + TS, E1);
        int cnt = lim - t0;
        for (int j = t; j < cnt; j += 256) tile[j] = pair[t0 + j];  // coalesced
        __syncthreads();
        if (active) {
            int hi = min(s1, lim);
            for (; i + 2 <= hi; i += 2) {
                int2 p0 = tile[i - t0];
                int2 p1 = tile[i + 1 - t0];
                H8 m0 = *(const H8*)(hin + (size_t)p0.x * HP + vo);
                H8 m1 = *(const H8*)(hin + (size_t)p1.x * HP + vo);
                float w0 = __int_as_float(p0.y);
                float w1 = __int_as_float(p1.y);
                float2 f;
                f = __half22float2(m0.a); acc[0] += f.x * w0; acc[1] += f.y * w0;
                f = __half22float2(m0.b); acc[2] += f.x * w0; acc[3] += f.y * w0;
                f = __half22float2(m0.c); acc[4] += f.x * w0; acc[5] += f.y * w0;
                f = __half22float2(m0.d); acc[6] += f.x * w0; acc[7] += f.y * w0;
                f = __half22float2(m1.a); acc[0] += f.x * w1; acc[1] += f.y * w1;
                f = __half22float2(m1.b); acc[2] += f.x * w1; acc[3] += f.y * w1;
                f = __half22float2(m1.c); acc[4] += f.x * w1; acc[5] += f.y * w1;
                f = __half22float2(m1.d); acc[6] += f.x * w1; acc[7] += f.y * w1;
            }
            if (i < hi) {
                int2 p0 = tile[i - t0];
                H8 m0 = *(const H8*)(hin + (size_t)p0.x * HP + vo);
                float w0 = __int_as_float(p0.y);
                float2 f;
                f = __half22float2(m0.a); acc[0] += f.x * w0; acc[1] += f.y * w0;
                f = __half22float2(m0.b); acc[2] += f.x * w0; acc[3] += f.y * w0;
                f = __half22float2(m0.c); acc[4] += f.x * w0; acc[5] += f.y * w0;
                f = __half22float2(m0.d); acc[6] += f.x * w0; acc[7] += f.y * w0;
                ++i;
            }
        }
        __syncthreads();
    }
    if (active) {
        if (FINAL) {
            float* o = houtf + (size_t)n * NC + vo;
            float4 v0 = {acc[0], acc[1], acc[2], acc[3]};
            float4 v1 = {acc[4], acc[5], acc[6], acc[7]};
            *(float4*)(o) = v0;
            *(float4*)(o + 4) = v1;
        } else {
            H8 v;
            v.a = f2h2(acc[0], acc[1]);
            v.b = f2h2(acc[2], acc[3]);
            v.c = f2h2(acc[4], acc[5]);
            v.d = f2h2(acc[6], acc[7]);
            *(H8*)(houth + (size_t)n * HP + vo) = v;
        }
    }
}

extern "C" void kernel_launch(void* const* d_in, const int* in_sizes, int n_in,
                              void* d_out, int out_size, void* d_ws, size_t ws_size,
                              hipStream_t stream) {
    const float* x  = (const float*)d_in[0];
    const int*   ei = (const int*)d_in[1];   // [2, NE]
    const float* w  = (const float*)d_in[2];
    const float* W  = (const float*)d_in[3]; // [128, 40]
    const int* row = ei;
    const int* col = ei + NE;
    float* out = (float*)d_out;              // [NN, NC] fp32, written by hop3 only

    // workspace (~38.8 MB): hb OVERLAYS {dc, done, dis, rank} — all dead once
    // k_scatter finishes; hb is first written by hop1 (after scatter).
    char* base = (char*)d_ws;
    __half* hb = (__half*)base;                                  // [NN, HP] fp16
    unsigned long long* dc = (unsigned long long*)base;          // [0, 800000)
    int* done = (int*)(base + (size_t)NN * 8);                   // [800000, +4)
    float* dis = (float*)(base + (size_t)NN * 8 + 16);
    unsigned char* rank = (unsigned char*)(base + (size_t)NN * 12 + 16);
    char* p = base + (size_t)NN * HP * 2;                        // end of hb region
    int*  offs = (int*)p;   p += (size_t)(NN + 4) * 4;
    int*  bsum = (int*)p;   p += 512 * 4;
    int2* pair = (int2*)p;  p += (size_t)NE * 8;                 // CSR {row, norm}
    __half* ha = (__half*)p;                                     // [NN, HP] fp16

    hipMemsetAsync(dc, 0, (size_t)NN * 8 + 16, stream);          // dc + done
    k_build<<<DB + NB, 256, 0, stream>>>(col, w, x, W, dc, rank, ha);
    k_scan<<<NB, 256, 0, stream>>>(dc, offs, bsum, dis, done);
    k_scatter<<<EB, 256, 0, stream>>>(row, col, w, dis, offs, bsum, rank, pair);

    k_hop<false><<<HB, 256, 0, stream>>>(offs, bsum, pair, ha, hb, nullptr);  // hop 1
    k_hop<false><<<HB, 256, 0, stream>>>(offs, bsum, pair, hb, ha, nullptr);  // hop 2
    k_hop<true ><<<HB, 256, 0, stream>>>(offs, bsum, pair, ha, nullptr, out); // hop 3
}

// Round 10
// 352.909 us; speedup vs baseline: 1.0398x; 1.0398x over previous
//
#include <hip/hip_runtime.h>
#include <hip/hip_fp16.h>

namespace {
constexpr int NN = 100000;   // nodes
constexpr int NE = 1600000;  // edges
constexpr int NF = 128;      // input feats
constexpr int NC = 40;       // classes (propagated dim after algebraic reorder)
constexpr int HP = 64;       // padded h row: 64 halfs = 128 B = exactly 1 L2 line
constexpr int NB = (NN + 255) / 256;  // node blocks = 391
constexpr int EB = (NE + 255) / 256;  // edge blocks = 6250
constexpr int NX = 8;                 // XCD replicas for the histogram
constexpr float FIX = 1048576.0f;     // 2^20 fixed-point scale for deg
constexpr int NPB = 51;               // nodes per hop block (51*5 = 255 threads)
constexpr int HB  = (NN + NPB - 1) / NPB;  // hop blocks = 1961
constexpr int TS  = 2048;             // staged pairs per tile (16 KB LDS)
}

struct alignas(16) H8 { __half2 a, b, c, d; };   // 8 halfs = one b128

__device__ inline __half2 f2h2(float x, float y) {
    return __halves2half2(__float2half_rn(x), __float2half_rn(y));
}

// Fused: blocks [0,NB) compute H0 = x@W -> fp16 padded rows; blocks [NB,..)
// histogram ONE u64 atomic/edge into the XCD-LOCAL replica dc[XCC_ID][c]
// with WORKGROUP scope: the RMW stays in the local L2 (device-scope atomics
// execute past L2 at the coherent point — that round-trip was the 21 G/s
// floor and the 32 B/atomic HBM write-through). Each replica line is only
// dirtied by its own XCD; end-of-kernel L2 writeback publishes it.
__global__ __launch_bounds__(256, 2) void k_build(const int* __restrict__ col,
                                                  const float* __restrict__ w,
                                                  const float* __restrict__ x,
                                                  const float* __restrict__ W,
                                                  unsigned long long* __restrict__ dc,
                                                  unsigned short* __restrict__ rank,
                                                  __half* __restrict__ h0) {
    if (blockIdx.x < (unsigned)NB) {
        int n = blockIdx.x * 256 + threadIdx.x;
        if (n >= NN) return;
        const float4* xr = (const float4*)(x + (size_t)n * NF);  // 32 float4
        const float4* W4 = (const float4*)W;                     // row k = 10 float4
        float acc[NC];
#pragma unroll
        for (int j = 0; j < NC; ++j) acc[j] = 0.f;
        for (int k4 = 0; k4 < NF / 4; ++k4) {
            float4 xv = xr[k4];
#pragma unroll
            for (int kk = 0; kk < 4; ++kk) {
                float xk = (kk == 0) ? xv.x : (kk == 1) ? xv.y : (kk == 2) ? xv.z : xv.w;
                int k = k4 * 4 + kk;
#pragma unroll
                for (int j4 = 0; j4 < 10; ++j4) {
                    float4 wq = W4[k * 10 + j4];   // wave-uniform address
                    acc[j4 * 4 + 0] += xk * wq.x;
                    acc[j4 * 4 + 1] += xk * wq.y;
                    acc[j4 * 4 + 2] += xk * wq.z;
                    acc[j4 * 4 + 3] += xk * wq.w;
                }
            }
        }
        H8* o = (H8*)(h0 + (size_t)n * HP);
#pragma unroll
        for (int g = 0; g < 5; ++g) {   // 5 x 8 halfs = 40
            H8 v;
            v.a = f2h2(acc[g * 8 + 0], acc[g * 8 + 1]);
            v.b = f2h2(acc[g * 8 + 2], acc[g * 8 + 3]);
            v.c = f2h2(acc[g * 8 + 4], acc[g * 8 + 5]);
            v.d = f2h2(acc[g * 8 + 6], acc[g * 8 + 7]);
            o[g] = v;
        }
    } else {
        int e = (blockIdx.x - NB) * 256 + threadIdx.x;
        if (e >= NE) return;
        unsigned xcd;
        asm volatile("s_getreg_b32 %0, hwreg(HW_REG_XCC_ID)" : "=s"(xcd));
        xcd &= 7;                              // wave-uniform, one XCD per workgroup
        int c = col[e];
        unsigned long long q = (unsigned long long)(unsigned)(w[e] * FIX + 0.5f);
        unsigned long long old = __hip_atomic_fetch_add(
            &dc[(size_t)xcd * NN + c], (1ull << 40) | q,
            __ATOMIC_RELAXED, __HIP_MEMORY_SCOPE_WORKGROUP);
        rank[e] = (unsigned short)((xcd << 8) | (unsigned)((old >> 40) & 0xff));
    }
}

// Per-node: sum the 8 replicas -> cnt, deg (-> dis); per-replica exclusive
// bases -> repbase (u8: max in-degree ~42). Then block-local exclusive scan
// of cnt -> offs + bsum; LAST block (device counter) scans bsum in place.
__global__ __launch_bounds__(256) void k_scan(const unsigned long long* __restrict__ dc,
                                              int* __restrict__ offs,
                                              int* __restrict__ bsum,
                                              float* __restrict__ dis,
                                              unsigned char* __restrict__ repbase,
                                              int* __restrict__ done) {
    __shared__ int s[256];
    __shared__ int amLast;
    int t = threadIdx.x, i = blockIdx.x * 256 + t;
    int v = 0;
    if (i < NN) {
        unsigned long long degfx = 0;
        int csum = 0;
#pragma unroll
        for (int r = 0; r < NX; ++r) {
            unsigned long long p = dc[(size_t)r * NN + i];
            repbase[(size_t)r * NN + i] = (unsigned char)csum;
            csum += (int)(p >> 40);
            degfx += (p & ((1ull << 40) - 1));
        }
        v = csum;
        float d = (float)degfx * (1.0f / FIX);
        dis[i] = (d > 0.f) ? rsqrtf(d) : 0.f;
    }
    s[t] = v;
    __syncthreads();
    for (int off = 1; off < 256; off <<= 1) {
        int add = (t >= off) ? s[t - off] : 0;
        __syncthreads();
        s[t] += add;
        __syncthreads();
    }
    if (i < NN) offs[i] = s[t] - v;
    if (t == 255) bsum[blockIdx.x] = s[255];
    // ---- last-block-done: scan bsum in place ----
    __threadfence();
    if (t == 0) amLast = (atomicAdd(done, 1) == NB - 1) ? 1 : 0;
    __syncthreads();
    if (!amLast) return;
    __threadfence();
    __shared__ int a[512], b[512];
    int i0 = t, i1 = t + 256;
    int v0 = (i0 < NB) ? bsum[i0] : 0;
    int v1 = (i1 < NB) ? bsum[i1] : 0;
    a[i0] = v0; a[i1] = v1;
    __syncthreads();
    int* cur = a; int* nxt = b;
    for (int off = 1; off < 512; off <<= 1) {
        nxt[i0] = cur[i0] + ((i0 >= off) ? cur[i0 - off] : 0);
        nxt[i1] = cur[i1] + ((i1 >= off) ? cur[i1 - off] : 0);
        __syncthreads();
        int* tmp = cur; cur = nxt; nxt = tmp;
    }
    if (i0 < NB) bsum[i0] = cur[i0] - v0;   // exclusive
    if (i1 < NB) bsum[i1] = cur[i1] - v1;
}

// CSR scatter, atomic-free:
// slot = offs[c] + bsum[c>>8] + repbase[xcd][c] + rank_in_replica.
// Fused {row, norm} as one 8 B NONTEMPORAL store.
__global__ __launch_bounds__(256) void k_scatter(const int* __restrict__ row,
                                                 const int* __restrict__ col,
                                                 const float* __restrict__ w,
                                                 const float* __restrict__ dis,
                                                 const int* __restrict__ offs,
                                                 const int* __restrict__ bsum,
                                                 const unsigned short* __restrict__ rank,
                                                 const unsigned char* __restrict__ repbase,
                                                 int2* __restrict__ pair) {
    int e = blockIdx.x * 256 + threadIdx.x;
    if (e >= NE) return;
    int r = row[e], c = col[e];
    unsigned short rk = rank[e];
    int p = offs[c] + bsum[c >> 8] + (int)repbase[(size_t)(rk >> 8) * NN + c]
          + (int)(rk & 0xff);
    unsigned long long v = (unsigned long long)(unsigned)r |
        ((unsigned long long)(unsigned)__float_as_int(dis[r] * w[e] * dis[c]) << 32);
    __builtin_nontemporal_store(v, (unsigned long long*)(pair + p));
}

// LDS-staged pull hop. Block = 51 nodes x 5 threads; block's CSR segment is
// contiguous -> stage pairs into LDS (1 coalesced VMEM/edge), gather h rows
// with one b128/lane. VMEM/edge = 6.
template <bool FINAL>
__global__ __launch_bounds__(256) void k_hop(const int* __restrict__ offs,
                                             const int* __restrict__ bsum,
                                             const int2* __restrict__ pair,
                                             const __half* __restrict__ hin,
                                             __half* __restrict__ houth,
                                             float* __restrict__ houtf) {
    __shared__ int2 tile[TS];
    __shared__ int erange[2];
    int t = threadIdx.x;
    int g = t / 5;                      // local node 0..50
    int n = blockIdx.x * NPB + g;
    bool active = (t < NPB * 5) && (n < NN);
    int vo = (t - g * 5) * 8;           // half offset 0,8,16,24,32
    int s0 = 0, s1 = 0;
    if (active) {
        s0 = offs[n] + bsum[n >> 8];
        int np = n + 1;
        s1 = (np == NN) ? NE : (offs[np] + bsum[np >> 8]);
    }
    if (t == 0) {
        int n0 = blockIdx.x * NPB;
        erange[0] = offs[n0] + bsum[n0 >> 8];
        int nl = n0 + NPB;
        erange[1] = (nl >= NN) ? NE : (offs[nl] + bsum[nl >> 8]);
    }
    __syncthreads();
    int E0 = erange[0], E1 = erange[1];
    float acc[8];
#pragma unroll
    for (int j = 0; j < 8; ++j) acc[j] = 0.f;
    int i = s0;
    for (int t0 = E0; t0 < E1; t0 += TS) {
        int lim = min(t0 + TS, E1);
        int cnt = lim - t0;
        for (int j = t; j < cnt; j += 256) tile[j] = pair[t0 + j];  // coalesced
        __syncthreads();
        if (active) {
            int hi = min(s1, lim);
            for (; i + 2 <= hi; i += 2) {
                int2 p0 = tile[i - t0];
                int2 p1 = tile[i + 1 - t0];
                H8 m0 = *(const H8*)(hin + (size_t)p0.x * HP + vo);
                H8 m1 = *(const H8*)(hin + (size_t)p1.x * HP + vo);
                float w0 = __int_as_float(p0.y);
                float w1 = __int_as_float(p1.y);
                float2 f;
                f = __half22float2(m0.a); acc[0] += f.x * w0; acc[1] += f.y * w0;
                f = __half22float2(m0.b); acc[2] += f.x * w0; acc[3] += f.y * w0;
                f = __half22float2(m0.c); acc[4] += f.x * w0; acc[5] += f.y * w0;
                f = __half22float2(m0.d); acc[6] += f.x * w0; acc[7] += f.y * w0;
                f = __half22float2(m1.a); acc[0] += f.x * w1; acc[1] += f.y * w1;
                f = __half22float2(m1.b); acc[2] += f.x * w1; acc[3] += f.y * w1;
                f = __half22float2(m1.c); acc[4] += f.x * w1; acc[5] += f.y * w1;
                f = __half22float2(m1.d); acc[6] += f.x * w1; acc[7] += f.y * w1;
            }
            if (i < hi) {
                int2 p0 = tile[i - t0];
                H8 m0 = *(const H8*)(hin + (size_t)p0.x * HP + vo);
                float w0 = __int_as_float(p0.y);
                float2 f;
                f = __half22float2(m0.a); acc[0] += f.x * w0; acc[1] += f.y * w0;
                f = __half22float2(m0.b); acc[2] += f.x * w0; acc[3] += f.y * w0;
                f = __half22float2(m0.c); acc[4] += f.x * w0; acc[5] += f.y * w0;
                f = __half22float2(m0.d); acc[6] += f.x * w0; acc[7] += f.y * w0;
                ++i;
            }
        }
        __syncthreads();
    }
    if (active) {
        if (FINAL) {
            float* o = houtf + (size_t)n * NC + vo;
            float4 v0 = {acc[0], acc[1], acc[2], acc[3]};
            float4 v1 = {acc[4], acc[5], acc[6], acc[7]};
            *(float4*)(o) = v0;
            *(float4*)(o + 4) = v1;
        } else {
            H8 v;
            v.a = f2h2(acc[0], acc[1]);
            v.b = f2h2(acc[2], acc[3]);
            v.c = f2h2(acc[4], acc[5]);
            v.d = f2h2(acc[6], acc[7]);
            *(H8*)(houth + (size_t)n * HP + vo) = v;
        }
    }
}

extern "C" void kernel_launch(void* const* d_in, const int* in_sizes, int n_in,
                              void* d_out, int out_size, void* d_ws, size_t ws_size,
                              hipStream_t stream) {
    const float* x  = (const float*)d_in[0];
    const int*   ei = (const int*)d_in[1];   // [2, NE]
    const float* w  = (const float*)d_in[2];
    const float* W  = (const float*)d_in[3]; // [128, 40]
    const int* row = ei;
    const int* col = ei + NE;
    float* out = (float*)d_out;              // [NN, NC] fp32, written by hop3 only

    // workspace: hb (12.8 MB) OVERLAYS {dc(6.4M), done, dis(0.4M),
    // rank(3.2M), repbase(0.8M)} = 10.8 MB — all dead once k_scatter
    // finishes; hb is first written by hop1 (after scatter).
    char* base = (char*)d_ws;
    __half* hb = (__half*)base;                                  // [NN, HP] fp16
    unsigned long long* dc = (unsigned long long*)base;          // [0, 6.4M)
    int* done = (int*)(base + (size_t)NX * NN * 8);              // +16B slot
    float* dis = (float*)(base + (size_t)NX * NN * 8 + 16);
    unsigned short* rank = (unsigned short*)(base + (size_t)NX * NN * 8 + 16
                                             + (size_t)NN * 4);
    unsigned char* repbase = (unsigned char*)((char*)rank + (size_t)NE * 2);
    char* p = base + (size_t)NN * HP * 2;                        // end of hb region
    int*  offs = (int*)p;   p += (size_t)(NN + 4) * 4;
    int*  bsum = (int*)p;   p += 512 * 4;
    int2* pair = (int2*)p;  p += (size_t)NE * 8;                 // CSR {row, norm}
    __half* ha = (__half*)p;                                     // [NN, HP] fp16

    hipMemsetAsync(dc, 0, (size_t)NX * NN * 8 + 16, stream);     // dc + done
    k_build<<<NB + EB, 256, 0, stream>>>(col, w, x, W, dc, rank, ha);
    k_scan<<<NB, 256, 0, stream>>>(dc, offs, bsum, dis, repbase, done);
    k_scatter<<<EB, 256, 0, stream>>>(row, col, w, dis, offs, bsum, rank, repbase, pair);

    k_hop<false><<<HB, 256, 0, stream>>>(offs, bsum, pair, ha, hb, nullptr);  // hop 1
    k_hop<false><<<HB, 256, 0, stream>>>(offs, bsum, pair, hb, ha, nullptr);  // hop 2
    k_hop<true ><<<HB, 256, 0, stream>>>(offs, bsum, pair, ha, nullptr, out); // hop 3
}